// Round 1
// baseline (1110.582 us; speedup 1.0000x reference)
//
#include <hip/hip_runtime.h>
#include <stdint.h>

#define S 2048
#define HID 3584
#define NH 16
#define NKV 8
#define DH 256
#define WINDOW 1024
#define SCALE 0.0625f
#define CAP 50.0f

typedef short s16x8 __attribute__((ext_vector_type(8)));
typedef float f32x4 __attribute__((ext_vector_type(4)));

__device__ __forceinline__ short f2bf(float f) {
  union { float f; uint32_t u; } c; c.f = f;
  uint32_t u = c.u;
  uint32_t r = (u + 0x7FFFu + ((u >> 16) & 1u)) >> 16;
  return (short)r;
}
__device__ __forceinline__ float bf2f(short s) {
  union { uint32_t u; float f; } c;
  c.u = ((uint32_t)(uint16_t)s) << 16;
  return c.f;
}

// ---------------- RoPE table: cos/sin per (s, i) ----------------
__global__ void rope_table_kernel(float2* __restrict__ tbl) {
  int idx = blockIdx.x * 256 + threadIdx.x;   // 2048*128 entries
  int s = idx >> 7, i = idx & 127;
  float inv = __expf(-(float)i * (9.210340371976184f / 128.0f)); // 10000^(-i/128)
  float fr = (float)s * inv;
  tbl[idx] = make_float2(cosf(fr), sinf(fr));
}

// ---------------- Fused QKV GEMM ----------------
// C = hs(2048x3584) * [Wq|Wk|Wv](3584x8192), bf16 MFMA, fp32 acc.
// q -> [H][S][D], k -> [KV][S][D], v -> transposed [KV][D][S]
__global__ __launch_bounds__(256)
void qkv_gemm_kernel(const float* __restrict__ hs,
                     const float* __restrict__ Wq,
                     const float* __restrict__ Wk,
                     const float* __restrict__ Wv,
                     short* __restrict__ qb, short* __restrict__ kbuf,
                     short* __restrict__ vtb)
{
  __shared__ __align__(16) short Alds[128][40];   // [m][k], pad to 40
  __shared__ __align__(16) short Blds[128][40];   // [n][k], pad to 40
  int bid = blockIdx.x;
  int bn = bid & 63, bm = bid >> 6;
  int m0 = bm * 128, n0 = bn * 128;
  const float* B; int bcol, region, Nb;
  if (n0 < 4096)      { B = Wq; bcol = n0;        region = 0; Nb = 4096; }
  else if (n0 < 6144) { B = Wk; bcol = n0 - 4096; region = 1; Nb = 2048; }
  else                { B = Wv; bcol = n0 - 6144; region = 2; Nb = 2048; }
  int tid = threadIdx.x;
  int w = tid >> 6, lane = tid & 63;
  int lr = lane & 15, lk = lane >> 4;
  int wm = (w >> 1) * 64, wn = (w & 1) * 64;
  f32x4 acc[4][4] = {};
  for (int k0 = 0; k0 < HID; k0 += 32) {
    __syncthreads();
    // stage A (128x32 fp32 -> bf16)
    #pragma unroll
    for (int it = 0; it < 4; ++it) {
      int flat = it * 1024 + tid * 4;
      int r = flat >> 5, c = flat & 31;
      float4 v = *(const float4*)&hs[(size_t)(m0 + r) * HID + k0 + c];
      Alds[r][c + 0] = f2bf(v.x); Alds[r][c + 1] = f2bf(v.y);
      Alds[r][c + 2] = f2bf(v.z); Alds[r][c + 3] = f2bf(v.w);
    }
    // stage B (32x128 fp32 -> bf16, transposed to [n][k])
    #pragma unroll
    for (int it = 0; it < 4; ++it) {
      int flat = it * 1024 + tid * 4;
      int r = flat >> 7, c = flat & 127;   // r = k, c = n
      float4 v = *(const float4*)&B[(size_t)(k0 + r) * Nb + bcol + c];
      Blds[c + 0][r] = f2bf(v.x); Blds[c + 1][r] = f2bf(v.y);
      Blds[c + 2][r] = f2bf(v.z); Blds[c + 3][r] = f2bf(v.w);
    }
    __syncthreads();
    s16x8 af[4], bfr[4];
    #pragma unroll
    for (int i = 0; i < 4; ++i)
      af[i] = *(const s16x8*)&Alds[wm + i * 16 + lr][lk * 8];
    #pragma unroll
    for (int i = 0; i < 4; ++i)
      bfr[i] = *(const s16x8*)&Blds[wn + i * 16 + lr][lk * 8];
    #pragma unroll
    for (int mi = 0; mi < 4; ++mi)
      #pragma unroll
      for (int ni = 0; ni < 4; ++ni)
        acc[mi][ni] = __builtin_amdgcn_mfma_f32_16x16x32_bf16(af[mi], bfr[ni], acc[mi][ni], 0, 0, 0);
  }
  // epilogue: scatter to q/k/vT layouts
  #pragma unroll
  for (int mi = 0; mi < 4; ++mi)
    #pragma unroll
    for (int ni = 0; ni < 4; ++ni)
      #pragma unroll
      for (int r = 0; r < 4; ++r) {
        int srow = m0 + wm + mi * 16 + lk * 4 + r;
        int ncol = n0 + wn + ni * 16 + lr;
        short bv = f2bf(acc[mi][ni][r]);
        if (region == 0) {
          int h = ncol >> 8, d = ncol & 255;
          qb[((size_t)h * S + srow) * DH + d] = bv;
        } else if (region == 1) {
          int c = ncol - 4096; int kv = c >> 8, d = c & 255;
          kbuf[((size_t)kv * S + srow) * DH + d] = bv;
        } else {
          int c = ncol - 6144; int kv = c >> 8, d = c & 255;
          vtb[((size_t)kv * DH + d) * S + srow] = bv;
        }
      }
}

// ---------------- RoPE (NeoX, in place on q and k) ----------------
__global__ void rope_kernel(short* __restrict__ qb, short* __restrict__ kbuf,
                            const float2* __restrict__ tbl)
{
  int gid = blockIdx.x * 256 + threadIdx.x;  // (NH+NKV)*S*16 chunk-threads
  int row = gid >> 4, ch = gid & 15;
  short* base = (row < NH * S) ? (qb + (size_t)row * DH)
                               : (kbuf + (size_t)(row - NH * S) * DH);
  int s = row & (S - 1);
  int i0 = ch * 8;
  s16x8 x1 = *(s16x8*)(base + i0);
  s16x8 x2 = *(s16x8*)(base + 128 + i0);
  s16x8 y1, y2;
  #pragma unroll
  for (int j = 0; j < 8; ++j) {
    float2 cs = tbl[s * 128 + i0 + j];
    float a = bf2f(x1[j]), b = bf2f(x2[j]);
    y1[j] = f2bf(a * cs.x - b * cs.y);
    y2[j] = f2bf(b * cs.x + a * cs.y);
  }
  *(s16x8*)(base + i0) = y1;
  *(s16x8*)(base + 128 + i0) = y2;
}

// ---------------- Attention (flash-style, GQA, window+causal, softcap) ----
// block = (head, q-tile of 64); 4 waves, each owns 16 q rows.
__global__ __launch_bounds__(256)
void attn_kernel(const short* __restrict__ qb, const short* __restrict__ kbuf,
                 const short* __restrict__ vtb, short* __restrict__ attnb)
{
  __shared__ __align__(16) short Klds[64][264];    // [k][d], pad 264
  __shared__ __align__(16) short Vlds[256][72];    // [d][k], pad 72
  __shared__ __align__(16) short Plds[4][16][72];  // per-wave P  [q][k]
  int bid = blockIdx.x;                 // 16 heads * 32 q-tiles
  int h = bid >> 5, qt = bid & 31;
  int kv = h >> 1;
  int q0 = qt * 64;
  int tid = threadIdx.x, w = tid >> 6, lane = tid & 63;
  int lr = lane & 15, lk = lane >> 4;
  int qrow_base = q0 + w * 16;
  // Q fragments (held in registers across all k-tiles)
  s16x8 qf[8];
  const short* qrow = qb + ((size_t)h * S + (qrow_base + lr)) * DH;
  #pragma unroll
  for (int kb = 0; kb < 8; ++kb)
    qf[kb] = *(const s16x8*)(qrow + kb * 32 + lk * 8);
  f32x4 acc_o[16] = {};
  float m_r[4], l_r[4];
  #pragma unroll
  for (int r = 0; r < 4; ++r) { m_r[r] = -1e30f; l_r[r] = 0.0f; }
  int tlo = (q0 >= WINDOW - 1) ? ((q0 - (WINDOW - 1)) >> 6) : 0;
  int thi = q0 >> 6;
  const short* kbase = kbuf + (size_t)kv * S * DH;
  const short* vbase = vtb + (size_t)kv * DH * S;
  for (int t = tlo; t <= thi; ++t) {
    int k0 = t * 64;
    __syncthreads();
    // stage K tile (contiguous 32KB) into [k][d]
    #pragma unroll
    for (int it = 0; it < 8; ++it) {
      int ch = it * 256 + tid;
      int r = ch >> 5, cg = ch & 31;
      *(s16x8*)&Klds[r][cg * 8] = *(const s16x8*)(kbase + (size_t)(k0 + r) * DH + cg * 8);
    }
    // stage V tile transposed-source [d][k]
    #pragma unroll
    for (int it = 0; it < 8; ++it) {
      int ch = it * 256 + tid;
      int r = ch >> 3, cg = ch & 7;
      *(s16x8*)&Vlds[r][cg * 8] = *(const s16x8*)(vbase + (size_t)r * S + k0 + cg * 8);
    }
    __syncthreads();
    // QK^T: 16 q rows x 64 k cols, K-dim = 256
    f32x4 sc[4] = {};
    #pragma unroll
    for (int kb = 0; kb < 8; ++kb)
      #pragma unroll
      for (int ni = 0; ni < 4; ++ni) {
        s16x8 b = *(const s16x8*)&Klds[ni * 16 + lr][kb * 32 + lk * 8];
        sc[ni] = __builtin_amdgcn_mfma_f32_16x16x32_bf16(qf[kb], b, sc[ni], 0, 0, 0);
      }
    // softcap + mask + online softmax
    bool validm[4][4];
    #pragma unroll
    for (int ni = 0; ni < 4; ++ni)
      #pragma unroll
      for (int r = 0; r < 4; ++r) {
        float sv = sc[ni][r] * SCALE;
        sv = CAP * tanhf(sv * (1.0f / CAP));
        int qg = qrow_base + lk * 4 + r;
        int kg = k0 + ni * 16 + lr;
        bool valid = (kg <= qg) && (qg - kg < WINDOW);
        validm[ni][r] = valid;
        sc[ni][r] = valid ? sv : -1e30f;
      }
    float alpha[4];
    #pragma unroll
    for (int r = 0; r < 4; ++r) {
      float mx = fmaxf(fmaxf(sc[0][r], sc[1][r]), fmaxf(sc[2][r], sc[3][r]));
      #pragma unroll
      for (int off = 1; off < 16; off <<= 1)
        mx = fmaxf(mx, __shfl_xor(mx, off, 64));
      float mnew = fmaxf(m_r[r], mx);
      alpha[r] = __expf(m_r[r] - mnew);
      m_r[r] = mnew;
      float sum = 0.0f;
      #pragma unroll
      for (int ni = 0; ni < 4; ++ni) {
        float p = validm[ni][r] ? __expf(sc[ni][r] - mnew) : 0.0f;
        sc[ni][r] = p;
        sum += p;
      }
      #pragma unroll
      for (int off = 1; off < 16; off <<= 1)
        sum += __shfl_xor(sum, off, 64);
      l_r[r] = l_r[r] * alpha[r] + sum;
    }
    // P -> per-wave LDS (bf16), then read back as A-fragments
    #pragma unroll
    for (int ni = 0; ni < 4; ++ni)
      #pragma unroll
      for (int r = 0; r < 4; ++r)
        Plds[w][lk * 4 + r][ni * 16 + lr] = f2bf(sc[ni][r]);
    __syncthreads();
    // rescale O
    #pragma unroll
    for (int df = 0; df < 16; ++df)
      #pragma unroll
      for (int r = 0; r < 4; ++r)
        acc_o[df][r] *= alpha[r];
    s16x8 pa0 = *(const s16x8*)&Plds[w][lr][lk * 8];
    s16x8 pa1 = *(const s16x8*)&Plds[w][lr][32 + lk * 8];
    // PV: O[16 x 256] += P[16 x 64] * V[64 x 256]
    #pragma unroll
    for (int df = 0; df < 16; ++df) {
      s16x8 b0 = *(const s16x8*)&Vlds[df * 16 + lr][lk * 8];
      s16x8 b1 = *(const s16x8*)&Vlds[df * 16 + lr][32 + lk * 8];
      acc_o[df] = __builtin_amdgcn_mfma_f32_16x16x32_bf16(pa0, b0, acc_o[df], 0, 0, 0);
      acc_o[df] = __builtin_amdgcn_mfma_f32_16x16x32_bf16(pa1, b1, acc_o[df], 0, 0, 0);
    }
  }
  // epilogue: attn[s][h*256+d]
  #pragma unroll
  for (int r = 0; r < 4; ++r) {
    int srow = qrow_base + lk * 4 + r;
    float inv = 1.0f / l_r[r];
    #pragma unroll
    for (int df = 0; df < 16; ++df)
      attnb[(size_t)srow * (NH * DH) + h * DH + df * 16 + lr] = f2bf(acc_o[df][r] * inv);
  }
}

// ---------------- Output GEMM: out = attn(2048x4096 bf16) * Wo(4096x3584 f32)
__global__ __launch_bounds__(256)
void out_gemm_kernel(const short* __restrict__ attnb, const float* __restrict__ Wo,
                     float* __restrict__ out)
{
  __shared__ __align__(16) short Alds[128][40];
  __shared__ __align__(16) short Blds[128][40];
  int bid = blockIdx.x;
  int bn = bid % 28, bm = bid / 28;
  int m0 = bm * 128, n0 = bn * 128;
  int tid = threadIdx.x;
  int w = tid >> 6, lane = tid & 63;
  int lr = lane & 15, lk = lane >> 4;
  int wm = (w >> 1) * 64, wn = (w & 1) * 64;
  f32x4 acc[4][4] = {};
  for (int k0 = 0; k0 < 4096; k0 += 32) {
    __syncthreads();
    // stage A (bf16 already)
    #pragma unroll
    for (int it = 0; it < 2; ++it) {
      int flat = it * 256 + tid;       // 512 chunks of 8
      int r = flat >> 2, cg = flat & 3;
      *(s16x8*)&Alds[r][cg * 8] = *(const s16x8*)&attnb[(size_t)(m0 + r) * 4096 + k0 + cg * 8];
    }
    // stage B (fp32 -> bf16, transposed)
    #pragma unroll
    for (int it = 0; it < 4; ++it) {
      int flat = it * 1024 + tid * 4;
      int r = flat >> 7, c = flat & 127;
      float4 v = *(const float4*)&Wo[(size_t)(k0 + r) * HID + n0 + c];
      Blds[c + 0][r] = f2bf(v.x); Blds[c + 1][r] = f2bf(v.y);
      Blds[c + 2][r] = f2bf(v.z); Blds[c + 3][r] = f2bf(v.w);
    }
    __syncthreads();
    s16x8 af[4], bfr[4];
    #pragma unroll
    for (int i = 0; i < 4; ++i)
      af[i] = *(const s16x8*)&Alds[wm + i * 16 + lr][lk * 8];
    #pragma unroll
    for (int i = 0; i < 4; ++i)
      bfr[i] = *(const s16x8*)&Blds[wn + i * 16 + lr][lk * 8];
    #pragma unroll
    for (int mi = 0; mi < 4; ++mi)
      #pragma unroll
      for (int ni = 0; ni < 4; ++ni)
        acc[mi][ni] = __builtin_amdgcn_mfma_f32_16x16x32_bf16(af[mi], bfr[ni], acc[mi][ni], 0, 0, 0);
  }
  #pragma unroll
  for (int mi = 0; mi < 4; ++mi)
    #pragma unroll
    for (int ni = 0; ni < 4; ++ni)
      #pragma unroll
      for (int r = 0; r < 4; ++r) {
        int srow = m0 + wm + mi * 16 + lk * 4 + r;
        int ncol = n0 + wn + ni * 16 + lr;
        out[(size_t)srow * HID + ncol] = acc[mi][ni][r];
      }
}

extern "C" void kernel_launch(void* const* d_in, const int* in_sizes, int n_in,
                              void* d_out, int out_size, void* d_ws, size_t ws_size,
                              hipStream_t stream) {
  const float* hs = (const float*)d_in[0];
  const float* Wq = (const float*)d_in[2];
  const float* Wk = (const float*)d_in[3];
  const float* Wv = (const float*)d_in[4];
  const float* Wo = (const float*)d_in[5];
  float* out = (float*)d_out;
  char* ws = (char*)d_ws;
  float2* tbl  = (float2*)(ws);                         // 2 MB
  short* qb    = (short*)(ws + 2097152);                // 16 MB
  short* kbuf  = (short*)(ws + 2097152 + 16777216);     // 8 MB
  short* vtb   = (short*)(ws + 2097152 + 16777216 + 8388608);   // 8 MB
  short* attnb = (short*)(ws + 2097152 + 16777216 + 8388608 + 8388608); // 16 MB

  hipLaunchKernelGGL(rope_table_kernel, dim3(1024), dim3(256), 0, stream, tbl);
  hipLaunchKernelGGL(qkv_gemm_kernel, dim3(1024), dim3(256), 0, stream,
                     hs, Wq, Wk, Wv, qb, kbuf, vtb);
  hipLaunchKernelGGL(rope_kernel, dim3(3072), dim3(256), 0, stream, qb, kbuf, tbl);
  hipLaunchKernelGGL(attn_kernel, dim3(512), dim3(256), 0, stream,
                     qb, kbuf, vtb, attnb);
  hipLaunchKernelGGL(out_gemm_kernel, dim3(448), dim3(256), 0, stream,
                     attnb, Wo, out);
}

// Round 2
// 490.013 us; speedup vs baseline: 2.2664x; 2.2664x over previous
//
#include <hip/hip_runtime.h>
#include <stdint.h>

#define S 2048
#define HID 3584
#define NH 16
#define NKV 8
#define DH 256
#define WINDOW 1024
#define SCALE 0.0625f
#define CAP 50.0f

typedef short s16x8 __attribute__((ext_vector_type(8)));
typedef float f32x4 __attribute__((ext_vector_type(4)));

__device__ __forceinline__ short f2bf(float f) {
  union { float f; uint32_t u; } c; c.f = f;
  uint32_t u = c.u;
  uint32_t r = (u + 0x7FFFu + ((u >> 16) & 1u)) >> 16;
  return (short)r;
}
__device__ __forceinline__ float bf2f(short s) {
  union { uint32_t u; float f; } c;
  c.u = ((uint32_t)(uint16_t)s) << 16;
  return c.f;
}
__device__ __forceinline__ void gll16(const void* g, void* l) {
  __builtin_amdgcn_global_load_lds((const __attribute__((address_space(1))) void*)g,
                                   (__attribute__((address_space(3))) void*)l, 16, 0, 0);
}

// ---------------- RoPE table ----------------
__global__ void rope_table_kernel(float2* __restrict__ tbl) {
  int idx = blockIdx.x * 256 + threadIdx.x;
  int s = idx >> 7, i = idx & 127;
  float inv = __expf(-(float)i * (9.210340371976184f / 128.0f));
  float fr = (float)s * inv;
  tbl[idx] = make_float2(cosf(fr), sinf(fr));
}

// ---------------- hs fp32 -> bf16 ----------------
__global__ void conv_hs_kernel(const float* __restrict__ src, short* __restrict__ dst) {
  int gid = blockIdx.x * 256 + threadIdx.x;
  float4 a = *(const float4*)&src[(size_t)gid * 8];
  float4 b = *(const float4*)&src[(size_t)gid * 8 + 4];
  s16x8 o;
  o[0] = f2bf(a.x); o[1] = f2bf(a.y); o[2] = f2bf(a.z); o[3] = f2bf(a.w);
  o[4] = f2bf(b.x); o[5] = f2bf(b.y); o[6] = f2bf(b.z); o[7] = f2bf(b.w);
  *(s16x8*)&dst[(size_t)gid * 8] = o;
}

// ---------------- W fp32 [K][N] -> bf16 [N][K] (transpose+convert) --------
__global__ __launch_bounds__(256)
void transpose_kernel(const float* __restrict__ src, short* __restrict__ dst,
                      int K, int N)
{
  __shared__ __align__(16) short t[64][76];
  int ntn = N >> 6;
  int tn = blockIdx.x % ntn, tk = blockIdx.x / ntn;
  int tid = threadIdx.x;
  // read phase: column chunks of 4 rows -> one 8B LDS write each
  int c = tid & 63, rg = tid >> 6;       // c: col within tile, rg: 0..3
  #pragma unroll
  for (int i = 0; i < 4; ++i) {
    int r0 = i * 16 + rg * 4;
    short tmp[4];
    #pragma unroll
    for (int j = 0; j < 4; ++j)
      tmp[j] = f2bf(src[(size_t)(tk * 64 + r0 + j) * N + tn * 64 + c]);
    *(short4*)&t[c][r0] = *(short4*)tmp;
  }
  __syncthreads();
  // write phase: rows of dst (n-major), 16B chunks
  #pragma unroll
  for (int it = 0; it < 2; ++it) {
    int flat = it * 256 + tid;
    int n = flat >> 3, kc = flat & 7;
    *(s16x8*)&dst[(size_t)(tn * 64 + n) * K + tk * 64 + kc * 8] = *(s16x8*)&t[n][kc * 8];
  }
}

// ---------------- Fused QKV GEMM (m97 structure) ----------------
// C = hsb(2048x3584 bf16) * Wt^T  where Wt is [8192][3584] bf16 (n-major)
__global__ __launch_bounds__(256)
void qkv_gemm_kernel(const short* __restrict__ hsb, const short* __restrict__ Wt,
                     short* __restrict__ qb, short* __restrict__ kbuf,
                     short* __restrict__ vtb)
{
  __shared__ __align__(16) short Asb[128 * 32];
  __shared__ __align__(16) short Bsb[128 * 32];
  int bid = blockIdx.x;
  int bn = bid & 63, bm = bid >> 6;
  int m0 = bm * 128, n0 = bn * 128;
  int tid = threadIdx.x, w = tid >> 6, lane = tid & 63;
  int lr = lane & 15, lk = lane >> 4;
  int wm = (w >> 1) * 64, wn = (w & 1) * 64;
  f32x4 acc[4][4] = {};
  for (int k0 = 0; k0 < HID; k0 += 32) {
    #pragma unroll
    for (int it = 0; it < 2; ++it) {
      int bo = (it * 4 + w) * 1024;          // wave-uniform LDS byte base
      int eo = (bo >> 1) + lane * 8;         // per-lane element offset
      int r = eo >> 5, c = eo & 31;
      gll16(&hsb[(size_t)(m0 + r) * HID + k0 + c], &Asb[bo >> 1]);
      gll16(&Wt[(size_t)(n0 + r) * HID + k0 + c], &Bsb[bo >> 1]);
    }
    __syncthreads();
    s16x8 af[4], bfr[4];
    #pragma unroll
    for (int i = 0; i < 4; ++i)
      af[i] = *(const s16x8*)&Asb[(wm + i * 16 + lr) * 32 + lk * 8];
    #pragma unroll
    for (int i = 0; i < 4; ++i)
      bfr[i] = *(const s16x8*)&Bsb[(wn + i * 16 + lr) * 32 + lk * 8];
    #pragma unroll
    for (int mi = 0; mi < 4; ++mi)
      #pragma unroll
      for (int ni = 0; ni < 4; ++ni)
        acc[mi][ni] = __builtin_amdgcn_mfma_f32_16x16x32_bf16(af[mi], bfr[ni], acc[mi][ni], 0, 0, 0);
    __syncthreads();
  }
  int region; // 0:q 1:k 2:v
  if (n0 < 4096) region = 0; else if (n0 < 6144) region = 1; else region = 2;
  #pragma unroll
  for (int mi = 0; mi < 4; ++mi)
    #pragma unroll
    for (int ni = 0; ni < 4; ++ni)
      #pragma unroll
      for (int r = 0; r < 4; ++r) {
        int srow = m0 + wm + mi * 16 + lk * 4 + r;
        int ncol = n0 + wn + ni * 16 + lr;
        short bv = f2bf(acc[mi][ni][r]);
        if (region == 0) {
          int h = ncol >> 8, d = ncol & 255;
          qb[((size_t)h * S + srow) * DH + d] = bv;
        } else if (region == 1) {
          int c = ncol - 4096; int kv = c >> 8, d = c & 255;
          kbuf[((size_t)kv * S + srow) * DH + d] = bv;
        } else {
          int c = ncol - 6144; int kv = c >> 8, d = c & 255;
          vtb[((size_t)kv * DH + d) * S + srow] = bv;
        }
      }
}

// ---------------- RoPE (NeoX, in place on q and k) ----------------
__global__ void rope_kernel(short* __restrict__ qb, short* __restrict__ kbuf,
                            const float2* __restrict__ tbl)
{
  int gid = blockIdx.x * 256 + threadIdx.x;
  int row = gid >> 4, ch = gid & 15;
  short* base = (row < NH * S) ? (qb + (size_t)row * DH)
                               : (kbuf + (size_t)(row - NH * S) * DH);
  int s = row & (S - 1);
  int i0 = ch * 8;
  s16x8 x1 = *(s16x8*)(base + i0);
  s16x8 x2 = *(s16x8*)(base + 128 + i0);
  s16x8 y1, y2;
  #pragma unroll
  for (int j = 0; j < 8; ++j) {
    float2 cs = tbl[s * 128 + i0 + j];
    float a = bf2f(x1[j]), b = bf2f(x2[j]);
    y1[j] = f2bf(a * cs.x - b * cs.y);
    y2[j] = f2bf(b * cs.x + a * cs.y);
  }
  *(s16x8*)(base + i0) = y1;
  *(s16x8*)(base + 128 + i0) = y2;
}

// ---------------- Attention (flash-style, GQA, window+causal, softcap) ----
__global__ __launch_bounds__(256)
void attn_kernel(const short* __restrict__ qb, const short* __restrict__ kbuf,
                 const short* __restrict__ vtb, short* __restrict__ attnb)
{
  __shared__ __align__(16) short Klds[64][264];
  __shared__ __align__(16) short Vlds[256][72];
  __shared__ __align__(16) short Plds[4][16][72];
  int bid = blockIdx.x;
  int h = bid >> 5, qt = bid & 31;
  int kv = h >> 1;
  int q0 = qt * 64;
  int tid = threadIdx.x, w = tid >> 6, lane = tid & 63;
  int lr = lane & 15, lk = lane >> 4;
  int qrow_base = q0 + w * 16;
  s16x8 qf[8];
  const short* qrow = qb + ((size_t)h * S + (qrow_base + lr)) * DH;
  #pragma unroll
  for (int kb = 0; kb < 8; ++kb)
    qf[kb] = *(const s16x8*)(qrow + kb * 32 + lk * 8);
  f32x4 acc_o[16] = {};
  float m_r[4], l_r[4];
  #pragma unroll
  for (int r = 0; r < 4; ++r) { m_r[r] = -1e30f; l_r[r] = 0.0f; }
  int tlo = (q0 >= WINDOW - 1) ? ((q0 - (WINDOW - 1)) >> 6) : 0;
  int thi = q0 >> 6;
  const short* kbase = kbuf + (size_t)kv * S * DH;
  const short* vbase = vtb + (size_t)kv * DH * S;
  for (int t = tlo; t <= thi; ++t) {
    int k0 = t * 64;
    __syncthreads();
    #pragma unroll
    for (int it = 0; it < 8; ++it) {
      int ch = it * 256 + tid;
      int r = ch >> 5, cg = ch & 31;
      *(s16x8*)&Klds[r][cg * 8] = *(const s16x8*)(kbase + (size_t)(k0 + r) * DH + cg * 8);
    }
    #pragma unroll
    for (int it = 0; it < 8; ++it) {
      int ch = it * 256 + tid;
      int r = ch >> 3, cg = ch & 7;
      *(s16x8*)&Vlds[r][cg * 8] = *(const s16x8*)(vbase + (size_t)r * S + k0 + cg * 8);
    }
    __syncthreads();
    f32x4 sc[4] = {};
    #pragma unroll
    for (int kb = 0; kb < 8; ++kb)
      #pragma unroll
      for (int ni = 0; ni < 4; ++ni) {
        s16x8 b = *(const s16x8*)&Klds[ni * 16 + lr][kb * 32 + lk * 8];
        sc[ni] = __builtin_amdgcn_mfma_f32_16x16x32_bf16(qf[kb], b, sc[ni], 0, 0, 0);
      }
    bool validm[4][4];
    #pragma unroll
    for (int ni = 0; ni < 4; ++ni)
      #pragma unroll
      for (int r = 0; r < 4; ++r) {
        float sv = sc[ni][r] * SCALE;
        sv = CAP * tanhf(sv * (1.0f / CAP));
        int qg = qrow_base + lk * 4 + r;
        int kg = k0 + ni * 16 + lr;
        bool valid = (kg <= qg) && (qg - kg < WINDOW);
        validm[ni][r] = valid;
        sc[ni][r] = valid ? sv : -1e30f;
      }
    float alpha[4];
    #pragma unroll
    for (int r = 0; r < 4; ++r) {
      float mx = fmaxf(fmaxf(sc[0][r], sc[1][r]), fmaxf(sc[2][r], sc[3][r]));
      #pragma unroll
      for (int off = 1; off < 16; off <<= 1)
        mx = fmaxf(mx, __shfl_xor(mx, off, 64));
      float mnew = fmaxf(m_r[r], mx);
      alpha[r] = __expf(m_r[r] - mnew);
      m_r[r] = mnew;
      float sum = 0.0f;
      #pragma unroll
      for (int ni = 0; ni < 4; ++ni) {
        float p = validm[ni][r] ? __expf(sc[ni][r] - mnew) : 0.0f;
        sc[ni][r] = p;
        sum += p;
      }
      #pragma unroll
      for (int off = 1; off < 16; off <<= 1)
        sum += __shfl_xor(sum, off, 64);
      l_r[r] = l_r[r] * alpha[r] + sum;
    }
    #pragma unroll
    for (int ni = 0; ni < 4; ++ni)
      #pragma unroll
      for (int r = 0; r < 4; ++r)
        Plds[w][lk * 4 + r][ni * 16 + lr] = f2bf(sc[ni][r]);
    __syncthreads();
    #pragma unroll
    for (int df = 0; df < 16; ++df)
      #pragma unroll
      for (int r = 0; r < 4; ++r)
        acc_o[df][r] *= alpha[r];
    s16x8 pa0 = *(const s16x8*)&Plds[w][lr][lk * 8];
    s16x8 pa1 = *(const s16x8*)&Plds[w][lr][32 + lk * 8];
    #pragma unroll
    for (int df = 0; df < 16; ++df) {
      s16x8 b0 = *(const s16x8*)&Vlds[df * 16 + lr][lk * 8];
      s16x8 b1 = *(const s16x8*)&Vlds[df * 16 + lr][32 + lk * 8];
      acc_o[df] = __builtin_amdgcn_mfma_f32_16x16x32_bf16(pa0, b0, acc_o[df], 0, 0, 0);
      acc_o[df] = __builtin_amdgcn_mfma_f32_16x16x32_bf16(pa1, b1, acc_o[df], 0, 0, 0);
    }
  }
  #pragma unroll
  for (int r = 0; r < 4; ++r) {
    int srow = qrow_base + lk * 4 + r;
    float inv = 1.0f / l_r[r];
    #pragma unroll
    for (int df = 0; df < 16; ++df)
      attnb[(size_t)srow * (NH * DH) + h * DH + df * 16 + lr] = f2bf(acc_o[df][r] * inv);
  }
}

// ---------------- Output GEMM (m97 structure) ----------------
// out(2048x3584 f32) = attnb(2048x4096 bf16) * WtO^T, WtO [3584][4096] bf16
__global__ __launch_bounds__(256)
void out_gemm_kernel(const short* __restrict__ attnb, const short* __restrict__ WtO,
                     float* __restrict__ out)
{
  __shared__ __align__(16) short Asb[128 * 32];
  __shared__ __align__(16) short Bsb[128 * 32];
  int bid = blockIdx.x;
  int bn = bid % 28, bm = bid / 28;
  int m0 = bm * 128, n0 = bn * 128;
  int tid = threadIdx.x, w = tid >> 6, lane = tid & 63;
  int lr = lane & 15, lk = lane >> 4;
  int wm = (w >> 1) * 64, wn = (w & 1) * 64;
  f32x4 acc[4][4] = {};
  for (int k0 = 0; k0 < 4096; k0 += 32) {
    #pragma unroll
    for (int it = 0; it < 2; ++it) {
      int bo = (it * 4 + w) * 1024;
      int eo = (bo >> 1) + lane * 8;
      int r = eo >> 5, c = eo & 31;
      gll16(&attnb[(size_t)(m0 + r) * 4096 + k0 + c], &Asb[bo >> 1]);
      gll16(&WtO[(size_t)(n0 + r) * 4096 + k0 + c], &Bsb[bo >> 1]);
    }
    __syncthreads();
    s16x8 af[4], bfr[4];
    #pragma unroll
    for (int i = 0; i < 4; ++i)
      af[i] = *(const s16x8*)&Asb[(wm + i * 16 + lr) * 32 + lk * 8];
    #pragma unroll
    for (int i = 0; i < 4; ++i)
      bfr[i] = *(const s16x8*)&Bsb[(wn + i * 16 + lr) * 32 + lk * 8];
    #pragma unroll
    for (int mi = 0; mi < 4; ++mi)
      #pragma unroll
      for (int ni = 0; ni < 4; ++ni)
        acc[mi][ni] = __builtin_amdgcn_mfma_f32_16x16x32_bf16(af[mi], bfr[ni], acc[mi][ni], 0, 0, 0);
    __syncthreads();
  }
  #pragma unroll
  for (int mi = 0; mi < 4; ++mi)
    #pragma unroll
    for (int ni = 0; ni < 4; ++ni)
      #pragma unroll
      for (int r = 0; r < 4; ++r) {
        int srow = m0 + wm + mi * 16 + lk * 4 + r;
        int ncol = n0 + wn + ni * 16 + lr;
        out[(size_t)srow * HID + ncol] = acc[mi][ni][r];
      }
}

extern "C" void kernel_launch(void* const* d_in, const int* in_sizes, int n_in,
                              void* d_out, int out_size, void* d_ws, size_t ws_size,
                              hipStream_t stream) {
  const float* hs = (const float*)d_in[0];
  const float* Wq = (const float*)d_in[2];
  const float* Wk = (const float*)d_in[3];
  const float* Wv = (const float*)d_in[4];
  const float* Wo = (const float*)d_in[5];
  float* out = (float*)d_out;
  char* ws = (char*)d_ws;
  size_t off = 0;
  float2* tbl  = (float2*)(ws + off); off += 2097152;            // 2 MB
  short* qb    = (short*)(ws + off);  off += 16777216;           // q  [H][S][D]
  short* kbuf  = (short*)(ws + off);  off += 8388608;            // k  [KV][S][D]
  short* vtb   = (short*)(ws + off);  off += 8388608;            // vT [KV][D][S]
  short* attnb = (short*)(ws + off);  off += 16777216;           // attn [S][4096]
  short* hsb   = (short*)(ws + off);  off += 14680064;           // hs bf16
  short* Wt    = (short*)(ws + off);  off += 58720256;           // [8192][3584]
  short* WtO   = (short*)(ws + off);  off += 29360128;           // [3584][4096]

  hipLaunchKernelGGL(rope_table_kernel, dim3(1024), dim3(256), 0, stream, tbl);
  hipLaunchKernelGGL(conv_hs_kernel, dim3(3584), dim3(256), 0, stream, hs, hsb);
  hipLaunchKernelGGL(transpose_kernel, dim3(64 * 56), dim3(256), 0, stream,
                     Wq, Wt, HID, 4096);
  hipLaunchKernelGGL(transpose_kernel, dim3(32 * 56), dim3(256), 0, stream,
                     Wk, Wt + (size_t)4096 * HID, HID, 2048);
  hipLaunchKernelGGL(transpose_kernel, dim3(32 * 56), dim3(256), 0, stream,
                     Wv, Wt + (size_t)6144 * HID, HID, 2048);
  hipLaunchKernelGGL(transpose_kernel, dim3(56 * 64), dim3(256), 0, stream,
                     Wo, WtO, 4096, HID);
  hipLaunchKernelGGL(qkv_gemm_kernel, dim3(1024), dim3(256), 0, stream,
                     hsb, Wt, qb, kbuf, vtb);
  hipLaunchKernelGGL(rope_kernel, dim3(3072), dim3(256), 0, stream, qb, kbuf, tbl);
  hipLaunchKernelGGL(attn_kernel, dim3(512), dim3(256), 0, stream,
                     qb, kbuf, vtb, attnb);
  hipLaunchKernelGGL(out_gemm_kernel, dim3(448), dim3(256), 0, stream,
                     attnb, WtO, out);
}